// Round 5
// baseline (156.301 us; speedup 1.0000x reference)
//
#include <hip/hip_runtime.h>

#define B_ 16
#define C_ 306
#define T_ 4000
#define M_ 128

typedef short bf16x8 __attribute__((ext_vector_type(8)));
typedef float f32x4 __attribute__((ext_vector_type(4)));

// W fragment array: [b][chunk(40)][m(128)][hl(2)][slot(8)] u16
// chunk = c>>3 (c = chunk*8 + slot); per-b size = 40*128*16 = 81920 u16
#define WF_PER_B 81920

// ---------- Kernel A: gate MLP -> W in MFMA-fragment order + scale[B,M] ------
__global__ __launch_bounds__(320)
void gate_kernel(const float* __restrict__ positions,   // [B,C,2]
                 const float* __restrict__ target,      // [M,2]
                 const float* __restrict__ w1,          // [3,32]
                 const float* __restrict__ b1,          // [32]
                 const float* __restrict__ w2,          // [32]
                 const float* __restrict__ b2,          // [1]
                 unsigned short* __restrict__ wf,       // fragment-order W
                 float* __restrict__ scale) {           // [B,M]
    const int b  = blockIdx.x >> 5;     // 512 blocks = B * 32
    const int mg = blockIdx.x & 31;     // group of 4 m
    const int tid = threadIdx.x;        // 0..319  (= c)

    __shared__ float s_w1[96], s_b1[32], s_w2[32];
    __shared__ float s_b2;
    __shared__ float s_tgt[8];
    __shared__ float s_part[4][5];
    __shared__ unsigned short s_frag[40 * 72];

    if (tid < 96) s_w1[tid] = w1[tid];
    if (tid < 32) { s_b1[tid] = b1[tid]; s_w2[tid] = w2[tid]; }
    if (tid == 256) s_b2 = b2[0];
    if (tid >= 312) s_tgt[tid - 312] = target[mg * 8 + (tid - 312)];
    __syncthreads();

    float px = 0.0f, py = 0.0f;
    if (tid < C_) {
        px = positions[(b * C_ + tid) * 2 + 0];
        py = positions[(b * C_ + tid) * 2 + 1];
    }

    float wv_[4];
#pragma unroll
    for (int mi = 0; mi < 4; ++mi) {
        float w = 0.0f;
        if (tid < C_) {
            const float dx = px - s_tgt[mi * 2 + 0];
            const float dy = py - s_tgt[mi * 2 + 1];
            const float d2 = dx * dx + dy * dy;
            const float s2 = __expf(-d2 * 3.125f);
            const float q  = s2 * s2;
            const float s1 = q * q;
            const float r  = s1 * s1;
            const float s0 = r * r;
            float acc = s_b2;
#pragma unroll
            for (int j = 0; j < 32; ++j) {
                float h = fmaf(s0, s_w1[j],
                          fmaf(s1, s_w1[32 + j],
                          fmaf(s2, s_w1[64 + j], s_b1[j])));
                acc = fmaf(fmaxf(h, 0.0f), s_w2[j], acc);
            }
            w = acc;
        }
        wv_[mi] = w;
    }

#pragma unroll
    for (int mi = 0; mi < 4; ++mi) {
        float s = wv_[mi];
#pragma unroll
        for (int off = 32; off > 0; off >>= 1) s += __shfl_down(s, off, 64);
        if ((tid & 63) == 0) s_part[mi][tid >> 6] = s;
    }

    const int chunk = tid >> 3;   // 0..39
    const int slot  = tid & 7;
#pragma unroll
    for (int mi = 0; mi < 4; ++mi) {
        const float w = wv_[mi];
        const unsigned int u = __float_as_uint(w);
        const unsigned short h = (unsigned short)(u >> 16);
        const float lof = w - __uint_as_float(u & 0xffff0000u);
        const unsigned short l = (unsigned short)(__float_as_uint(lof) >> 16);
        s_frag[chunk * 72 + mi * 16 + 0 + slot] = h;
        s_frag[chunk * 72 + mi * 16 + 8 + slot] = l;
    }
    __syncthreads();

    if (tid < 4) {
        float tot = s_part[tid][0] + s_part[tid][1] + s_part[tid][2]
                  + s_part[tid][3] + s_part[tid][4];
        scale[b * M_ + mg * 4 + tid] = 1.0f / (tot + 1e-8f);
    }

    {
        const int ch = tid >> 3;       // 0..39
        const int g  = tid & 7;        // (mi = g>>1, hl = g&1)
        const uint4 v = *(const uint4*)(s_frag + ch * 72 + g * 8);
        unsigned short* dst = wf + (size_t)b * WF_PER_B
                            + (size_t)ch * 2048 + mg * 64 + g * 8;
        *(uint4*)dst = v;
    }
}

// ---------- Kernel B: MFMA GEMM  out[b][m][t] = scale[b][m] * sum_c w*x ------
// 512 threads (8 waves), full-K LDS tile, ONE barrier.
// Round 0-4 synthesis: barrier count / waitcnt style / prefetch depth were
// all perf-neutral (45-49us every variant); counters showed nothing busy
// (MFMA 11%, VALU 10%, HBM 21%) = latency-bound. Every prior variant had
// EITHER <=2 waves/SIMD with full ILP (80KB LDS, 256thr) OR 4 waves/SIMD
// with crippled ILP (launch_bounds(256,4) -> 56 VGPR). This version has
// both: 8 waves/block x 2 blocks/CU = 4 waves/SIMD, VGPR cap 128 (~95 used).
// Per-wave tile m32 x t32 (acc[2][2]); memory volumes and per-output FP op
// order unchanged -> absmax must stay bitwise 0.001953125.
// LDS layout: word addr = t*320 + hl*160 + (p ^ ((t&7)<<2)), p = c-pair
// index 0..159. Row stride 320 == 0 mod 32. Write banks = cp ^ swz with cp
// spanning 0..31 per wave -> all 32 banks, 2 lanes/bank = conflict-free
// (fixes round-4's 4.5M conflicts from 4-value cp). Read b128 groups cover
// all 32 banks at depth 8 = optimal.
#define RS4 320   // row stride in u32 words

__global__ __launch_bounds__(512, 4)
void merge_gemm(const float* __restrict__ x,            // [B,C,T]
                const unsigned short* __restrict__ wf,  // fragment-order W
                const float* __restrict__ scale,        // [B,M]
                float* __restrict__ out) {              // [B,M,T]
    const int t0 = blockIdx.x * 64;
    const int b  = blockIdx.y;
    const int tid  = threadIdx.x;     // 0..511
    const int lane = tid & 63;
    const int wv   = tid >> 6;        // 0..7
    const int tquad = lane >> 4;      // 0..3
    const int tsub  = lane & 15;      // 0..15

    __shared__ __align__(16) unsigned int sX[64 * RS4];  // 81920 B

    const float* xb = x + (size_t)b * C_ * T_;
    const unsigned short* wfB = wf + (size_t)b * WF_PER_B;

    const int mw  = (wv & 3) * 32;   // wave m-origin (4 m-groups of 32)
    const int tw2 = (wv >> 2) * 32;  // wave t-origin (2 t-groups of 32)

    auto loadW = [&](int k, bf16x8* ah_, bf16x8* al_) {
#pragma unroll
        for (int mi = 0; mi < 2; ++mi) {
            const size_t aoff = ((size_t)(k * 4 + tquad) * 128
                               + (mw + mi * 16 + tsub)) * 16;
            ah_[mi] = *(const bf16x8*)(wfB + aoff);
            al_[mi] = *(const bf16x8*)(wfB + aoff + 8);
        }
    };

    // ---------------- load + pack phase (full K resident) ----------------
    // thread owns c-pairs p = j*32 + cp (j=0..4) at t-quad TQ
    const int cp = tid & 31;         // 0..31  (full 5-bit bank spread)
    const int TQ = tid >> 5;         // 0..15
    const float* xcol = xb + min(t0 + TQ * 4, T_ - 4);

    bf16x8 ah[2], al[2];

    // issue all 10 x loads first (independent, deep in flight), then W(0)
    float4 va[5], vb[5];
#pragma unroll
    for (int j = 0; j < 5; ++j) {
        const int c = (j * 32 + cp) * 2;
        va[j] = *(const float4*)(xcol + (size_t)min(c,     C_ - 1) * T_);
        vb[j] = *(const float4*)(xcol + (size_t)min(c + 1, C_ - 1) * T_);
    }
    loadW(0, ah, al);   // ready by barrier exit; issued after x so pack
                        // waits don't drain it

#pragma unroll
    for (int j = 0; j < 5; ++j) {
        const int p = j * 32 + cp;
        const float* fa = (const float*)&va[j];
        const float* fb = (const float*)&vb[j];
#pragma unroll
        for (int tt = 0; tt < 4; ++tt) {
            const int t = TQ * 4 + tt;
            const int q = t * RS4 + (p ^ ((t & 7) << 2));
            const unsigned int ua = __float_as_uint(fa[tt]);
            const unsigned int ub = __float_as_uint(fb[tt]);
            const float la = fa[tt] - __uint_as_float(ua & 0xffff0000u);
            const float lb = fb[tt] - __uint_as_float(ub & 0xffff0000u);
            // low16 = hi(c_even), high16 = hi(c_odd)  (hw-verified perm)
            sX[q]       = __builtin_amdgcn_perm(ub, ua, 0x07060302u);
            sX[q + 160] = __builtin_amdgcn_perm(__float_as_uint(lb),
                                                __float_as_uint(la),
                                                0x07060302u);
        }
    }
    __syncthreads();     // the ONLY barrier in this kernel

    // ---------------- compute phase: no synchronization ----------------
    f32x4 acc[2][2];
#pragma unroll
    for (int i = 0; i < 2; ++i)
#pragma unroll
        for (int j = 0; j < 2; ++j) acc[i][j] = (f32x4){0.f, 0.f, 0.f, 0.f};

    // per-ti fragment row bases (t fixed across k)
    int rbase[2], tswz[2];
#pragma unroll
    for (int ti = 0; ti < 2; ++ti) {
        const int t = tw2 + ti * 16 + tsub;
        rbase[ti] = t * RS4;
        tswz[ti]  = (t & 7) << 2;
    }

#pragma unroll
    for (int k = 0; k < 10; ++k) {
        bf16x8 bh[2], bl[2];
#pragma unroll
        for (int ti = 0; ti < 2; ++ti) {
            const int q = rbase[ti] + ((k * 16 + tquad * 4) ^ tswz[ti]);
            bh[ti] = *(const bf16x8*)(&sX[q]);
            bl[ti] = *(const bf16x8*)(&sX[q + 160]);
        }

        // 12 MFMAs, product-major; per-acc add order (hh, hl, lh) unchanged
#pragma unroll
        for (int mi = 0; mi < 2; ++mi)
#pragma unroll
            for (int ti = 0; ti < 2; ++ti)
                acc[mi][ti] = __builtin_amdgcn_mfma_f32_16x16x32_bf16(
                    ah[mi], bh[ti], acc[mi][ti], 0, 0, 0);
#pragma unroll
        for (int mi = 0; mi < 2; ++mi)
#pragma unroll
            for (int ti = 0; ti < 2; ++ti)
                acc[mi][ti] = __builtin_amdgcn_mfma_f32_16x16x32_bf16(
                    ah[mi], bl[ti], acc[mi][ti], 0, 0, 0);
#pragma unroll
        for (int mi = 0; mi < 2; ++mi)
#pragma unroll
            for (int ti = 0; ti < 2; ++ti)
                acc[mi][ti] = __builtin_amdgcn_mfma_f32_16x16x32_bf16(
                    al[mi], bh[ti], acc[mi][ti], 0, 0, 0);

        if (k < 9) loadW(k + 1, ah, al);   // refill after last use; next
                                           // step's MFMAs hide L2 latency
    }

    // ---- epilogue: fold scale, store (C/D: col = lane&15, row = quad*4+reg)
#pragma unroll
    for (int mi = 0; mi < 2; ++mi) {
        const int mbase = mw + mi * 16 + tquad * 4;
        const float4 sc = *(const float4*)(scale + b * M_ + mbase);
        float* op = out + ((size_t)b * M_ + mbase) * T_;
#pragma unroll
        for (int ti = 0; ti < 2; ++ti) {
            const int tg = t0 + tw2 + ti * 16 + tsub;
            if (tg < T_) {
                op[(size_t)0 * T_ + tg] = acc[mi][ti][0] * sc.x;
                op[(size_t)1 * T_ + tg] = acc[mi][ti][1] * sc.y;
                op[(size_t)2 * T_ + tg] = acc[mi][ti][2] * sc.z;
                op[(size_t)3 * T_ + tg] = acc[mi][ti][3] * sc.w;
            }
        }
    }
}

extern "C" void kernel_launch(void* const* d_in, const int* in_sizes, int n_in,
                              void* d_out, int out_size, void* d_ws, size_t ws_size,
                              hipStream_t stream) {
    const float* x         = (const float*)d_in[0];
    const float* positions = (const float*)d_in[1];
    const float* target    = (const float*)d_in[2];
    const float* w1        = (const float*)d_in[3];
    const float* b1        = (const float*)d_in[4];
    const float* w2        = (const float*)d_in[5];
    const float* b2        = (const float*)d_in[6];
    float* out = (float*)d_out;

    float* scale = (float*)d_ws;                             // B*M floats
    unsigned short* wf = (unsigned short*)(scale + B_ * M_); // 16*81920 u16

    gate_kernel<<<B_ * 32, 320, 0, stream>>>(positions, target, w1, b1, w2, b2,
                                             wf, scale);

    dim3 grid((T_ + 63) / 64, B_);
    merge_gemm<<<grid, 512, 0, stream>>>(x, wf, scale, out);
}

// Round 6
// 143.909 us; speedup vs baseline: 1.0861x; 1.0861x over previous
//
#include <hip/hip_runtime.h>

#define B_ 16
#define C_ 306
#define T_ 4000
#define M_ 128

typedef short bf16x8 __attribute__((ext_vector_type(8)));
typedef float f32x4 __attribute__((ext_vector_type(4)));

// W fragment array: [b][chunk(40)][m(128)][hl(2)][slot(8)] u16
// chunk = c>>3 (c = chunk*8 + slot); per-b size = 40*128*16 = 81920 u16
#define WF_PER_B 81920

// ---------- Kernel A: gate MLP -> W in MFMA-fragment order + scale[B,M] ------
__global__ __launch_bounds__(320)
void gate_kernel(const float* __restrict__ positions,   // [B,C,2]
                 const float* __restrict__ target,      // [M,2]
                 const float* __restrict__ w1,          // [3,32]
                 const float* __restrict__ b1,          // [32]
                 const float* __restrict__ w2,          // [32]
                 const float* __restrict__ b2,          // [1]
                 unsigned short* __restrict__ wf,       // fragment-order W
                 float* __restrict__ scale) {           // [B,M]
    const int b  = blockIdx.x >> 5;     // 512 blocks = B * 32
    const int mg = blockIdx.x & 31;     // group of 4 m
    const int tid = threadIdx.x;        // 0..319  (= c)

    __shared__ float s_w1[96], s_b1[32], s_w2[32];
    __shared__ float s_b2;
    __shared__ float s_tgt[8];
    __shared__ float s_part[4][5];
    __shared__ unsigned short s_frag[40 * 72];

    if (tid < 96) s_w1[tid] = w1[tid];
    if (tid < 32) { s_b1[tid] = b1[tid]; s_w2[tid] = w2[tid]; }
    if (tid == 256) s_b2 = b2[0];
    if (tid >= 312) s_tgt[tid - 312] = target[mg * 8 + (tid - 312)];
    __syncthreads();

    float px = 0.0f, py = 0.0f;
    if (tid < C_) {
        px = positions[(b * C_ + tid) * 2 + 0];
        py = positions[(b * C_ + tid) * 2 + 1];
    }

    float wv_[4];
#pragma unroll
    for (int mi = 0; mi < 4; ++mi) {
        float w = 0.0f;
        if (tid < C_) {
            const float dx = px - s_tgt[mi * 2 + 0];
            const float dy = py - s_tgt[mi * 2 + 1];
            const float d2 = dx * dx + dy * dy;
            const float s2 = __expf(-d2 * 3.125f);
            const float q  = s2 * s2;
            const float s1 = q * q;
            const float r  = s1 * s1;
            const float s0 = r * r;
            float acc = s_b2;
#pragma unroll
            for (int j = 0; j < 32; ++j) {
                float h = fmaf(s0, s_w1[j],
                          fmaf(s1, s_w1[32 + j],
                          fmaf(s2, s_w1[64 + j], s_b1[j])));
                acc = fmaf(fmaxf(h, 0.0f), s_w2[j], acc);
            }
            w = acc;
        }
        wv_[mi] = w;
    }

#pragma unroll
    for (int mi = 0; mi < 4; ++mi) {
        float s = wv_[mi];
#pragma unroll
        for (int off = 32; off > 0; off >>= 1) s += __shfl_down(s, off, 64);
        if ((tid & 63) == 0) s_part[mi][tid >> 6] = s;
    }

    const int chunk = tid >> 3;   // 0..39
    const int slot  = tid & 7;
#pragma unroll
    for (int mi = 0; mi < 4; ++mi) {
        const float w = wv_[mi];
        const unsigned int u = __float_as_uint(w);
        const unsigned short h = (unsigned short)(u >> 16);
        const float lof = w - __uint_as_float(u & 0xffff0000u);
        const unsigned short l = (unsigned short)(__float_as_uint(lof) >> 16);
        s_frag[chunk * 72 + mi * 16 + 0 + slot] = h;
        s_frag[chunk * 72 + mi * 16 + 8 + slot] = l;
    }
    __syncthreads();

    if (tid < 4) {
        float tot = s_part[tid][0] + s_part[tid][1] + s_part[tid][2]
                  + s_part[tid][3] + s_part[tid][4];
        scale[b * M_ + mg * 4 + tid] = 1.0f / (tot + 1e-8f);
    }

    {
        const int ch = tid >> 3;       // 0..39
        const int g  = tid & 7;        // (mi = g>>1, hl = g&1)
        const uint4 v = *(const uint4*)(s_frag + ch * 72 + g * 8);
        unsigned short* dst = wf + (size_t)b * WF_PER_B
                            + (size_t)ch * 2048 + mg * 64 + g * 8;
        *(uint4*)dst = v;
    }
}

// ---------- Kernel B: MFMA GEMM  out[b][m][t] = scale[b][m] * sum_c w*x ------
// t-tile 256, 512 threads, 1 block/CU (grid 16x16), BK=64 double-buffered LDS
// (128 KB), 5 K-steps, round-0-style schedule (reg-prefetch next x during
// MFMAs, lgkm-only barrier, in-place W refill).
// WHY: rounds 0-5 falsified barrier style, prefetch depth and occupancy as
// the limiter; time tracks bytes-per-DRAM-row-visit of the x fetch (t=128
// ~36us @512B runs, t=64 ~48us @256B, 16B-granular ~48us; FETCH_SIZE
// constant). Here each (c,block) row-visit is a full 1 KB: per load instr
// 32 lanes read 512 B contiguous, and the adjacent 512 B chunk is issued
// back-to-back.
// LDS: sX[buf][plane][t*32 + (pair ^ ((t>>2 & 7)<<2))]; b128 reads stay
// aligned+contiguous (swz bits 2-4 only, pair-quad aligned); write
// conflicts bounded at 4-way. Per-acc FP op order (k-chunks ascending;
// hh,hl,lh per chunk) and pack arithmetic unchanged -> bitwise-identical
// output, absmax must stay 0.001953125.
#define TW 256      // t-tile
#define PL 8192     // plane size in u32 words (256 t * 32 pairs)

__global__ __launch_bounds__(512, 2)
void merge_gemm(const float* __restrict__ x,            // [B,C,T]
                const unsigned short* __restrict__ wf,  // fragment-order W
                const float* __restrict__ scale,        // [B,M]
                float* __restrict__ out) {              // [B,M,T]
    const int t0 = blockIdx.x * TW;
    const int b  = blockIdx.y;
    const int tid  = threadIdx.x;     // 0..511
    const int lane = tid & 63;
    const int wv   = tid >> 6;        // 0..7
    const int tquad = lane >> 4;      // 0..3
    const int tsub  = lane & 15;      // 0..15

    __shared__ __align__(16) unsigned int sX[2][2][PL];   // 131072 B

    const float* xb = x + (size_t)b * C_ * T_;
    const unsigned short* wfB = wf + (size_t)b * WF_PER_B;

    const int mw  = (wv & 3) * 32;    // wave m-origin (4 m-groups of 32)
    const int twv = (wv >> 2) * 128;  // wave t-origin (2 t-groups of 128)

    // staging ownership: cp = tid>>5 (0..15), TQ = tid&31; thread covers
    // pairs {cp, cp+16} x t-quads {TQ, TQ+32}. Per load instr a wave's
    // 64 lanes read 2 rows x 512 B contiguous; the s=1 chunk (adjacent
    // 512 B of the same rows) is issued immediately after.
    const int cp = tid >> 5;          // 0..15
    const int TQ = tid & 31;          // 0..31

    auto loadX = [&](int k, float4 (&A)[2][2], float4 (&B)[2][2]) {
#pragma unroll
        for (int h = 0; h < 2; ++h) {
            const int p  = cp + 16 * h;
            const int c0 = k * 64 + 2 * p;
#pragma unroll
            for (int s = 0; s < 2; ++s) {
                const int tq = TQ + 32 * s;
                const float* col = xb + min(t0 + tq * 4, T_ - 4);
                A[h][s] = *(const float4*)(col + (size_t)min(c0,     C_ - 1) * T_);
                B[h][s] = *(const float4*)(col + (size_t)min(c0 + 1, C_ - 1) * T_);
            }
        }
    };
    auto packX = [&](const float4 (&A)[2][2], const float4 (&B)[2][2], int buf) {
#pragma unroll
        for (int h = 0; h < 2; ++h) {
            const int p = cp + 16 * h;
#pragma unroll
            for (int s = 0; s < 2; ++s) {
                const int tq = TQ + 32 * s;
                const int swz = (tq & 7) << 2;
                const float* fa = (const float*)&A[h][s];
                const float* fb = (const float*)&B[h][s];
#pragma unroll
                for (int tt = 0; tt < 4; ++tt) {
                    const int t = tq * 4 + tt;
                    const int addr = t * 32 + (p ^ swz);
                    const unsigned int ua = __float_as_uint(fa[tt]);
                    const unsigned int ub = __float_as_uint(fb[tt]);
                    const float la = fa[tt] - __uint_as_float(ua & 0xffff0000u);
                    const float lb = fb[tt] - __uint_as_float(ub & 0xffff0000u);
                    // low16 = hi(c_even), high16 = hi(c_odd)
                    sX[buf][0][addr] = __builtin_amdgcn_perm(ub, ua, 0x07060302u);
                    sX[buf][1][addr] = __builtin_amdgcn_perm(__float_as_uint(lb),
                                                             __float_as_uint(la),
                                                             0x07060302u);
                }
            }
        }
    };
    // W for step k: both 32-k chunks (kk=0,1), m-tile 32 -> 2 mi
    auto loadW = [&](int k, bf16x8 (&ah_)[2][2], bf16x8 (&al_)[2][2]) {
#pragma unroll
        for (int kk = 0; kk < 2; ++kk)
#pragma unroll
            for (int mi = 0; mi < 2; ++mi) {
                const size_t aoff = ((size_t)(k * 8 + kk * 4 + tquad) * 128
                                   + (mw + mi * 16 + tsub)) * 16;
                ah_[kk][mi] = *(const bf16x8*)(wfB + aoff);
                al_[kk][mi] = *(const bf16x8*)(wfB + aoff + 8);
            }
    };

    // ---- prologue ----
    f32x4 acc[2][8];
#pragma unroll
    for (int i = 0; i < 2; ++i)
#pragma unroll
        for (int j = 0; j < 8; ++j) acc[i][j] = (f32x4){0.f, 0.f, 0.f, 0.f};

    bf16x8 ah[2][2], al[2][2];
    {
        float4 A0[2][2], B0[2][2];
        loadX(0, A0, B0);
        loadW(0, ah, al);
        packX(A0, B0, 0);
    }
    asm volatile("s_waitcnt lgkmcnt(0)" ::: "memory");
    __builtin_amdgcn_s_barrier();
    asm volatile("" ::: "memory");

    // per-ti read bases (t fixed across k)
    int rbase[8], tswz[8];
#pragma unroll
    for (int ti = 0; ti < 8; ++ti) {
        const int t = twv + ti * 16 + tsub;
        rbase[ti] = t * 32;
        tswz[ti]  = ((t >> 2) & 7) << 2;
    }

#pragma unroll
    for (int k = 0; k < 5; ++k) {
        float4 An[2][2], Bn[2][2];
        if (k < 4) loadX(k + 1, An, Bn);   // in flight under the MFMAs

        const int buf = k & 1;
#pragma unroll
        for (int kk = 0; kk < 2; ++kk) {
            const int Q = kk * 16 + tquad * 4;   // pair-quad base
#pragma unroll
            for (int ti = 0; ti < 8; ++ti) {
                const int a = rbase[ti] + (Q ^ tswz[ti]);
                const bf16x8 bh = *(const bf16x8*)(&sX[buf][0][a]);
                const bf16x8 bl = *(const bf16x8*)(&sX[buf][1][a]);
                // per-acc order hh, hl, lh (bitwise-identical chain)
#pragma unroll
                for (int mi = 0; mi < 2; ++mi)
                    acc[mi][ti] = __builtin_amdgcn_mfma_f32_16x16x32_bf16(
                        ah[kk][mi], bh, acc[mi][ti], 0, 0, 0);
#pragma unroll
                for (int mi = 0; mi < 2; ++mi)
                    acc[mi][ti] = __builtin_amdgcn_mfma_f32_16x16x32_bf16(
                        ah[kk][mi], bl, acc[mi][ti], 0, 0, 0);
#pragma unroll
                for (int mi = 0; mi < 2; ++mi)
                    acc[mi][ti] = __builtin_amdgcn_mfma_f32_16x16x32_bf16(
                        al[kk][mi], bh, acc[mi][ti], 0, 0, 0);
            }
        }

        if (k < 4) {
            loadW(k + 1, ah, al);          // L2-hot; covered by barrier+reads
            packX(An, Bn, buf ^ 1);        // other buffer: safe, all waves
                                           // passed the previous barrier
            asm volatile("s_waitcnt lgkmcnt(0)" ::: "memory");
            __builtin_amdgcn_s_barrier();
            asm volatile("" ::: "memory");
        }
    }

    // ---- epilogue: fold scale, store (C/D: col = lane&15, row = quad*4+reg)
#pragma unroll
    for (int mi = 0; mi < 2; ++mi) {
        const int mbase = mw + mi * 16 + tquad * 4;
        const float4 sc = *(const float4*)(scale + b * M_ + mbase);
        float* op = out + ((size_t)b * M_ + mbase) * T_;
#pragma unroll
        for (int ti = 0; ti < 8; ++ti) {
            const int tg = t0 + twv + ti * 16 + tsub;
            if (tg < T_) {
                op[(size_t)0 * T_ + tg] = acc[mi][ti][0] * sc.x;
                op[(size_t)1 * T_ + tg] = acc[mi][ti][1] * sc.y;
                op[(size_t)2 * T_ + tg] = acc[mi][ti][2] * sc.z;
                op[(size_t)3 * T_ + tg] = acc[mi][ti][3] * sc.w;
            }
        }
    }
}

extern "C" void kernel_launch(void* const* d_in, const int* in_sizes, int n_in,
                              void* d_out, int out_size, void* d_ws, size_t ws_size,
                              hipStream_t stream) {
    const float* x         = (const float*)d_in[0];
    const float* positions = (const float*)d_in[1];
    const float* target    = (const float*)d_in[2];
    const float* w1        = (const float*)d_in[3];
    const float* b1        = (const float*)d_in[4];
    const float* w2        = (const float*)d_in[5];
    const float* b2        = (const float*)d_in[6];
    float* out = (float*)d_out;

    float* scale = (float*)d_ws;                             // B*M floats
    unsigned short* wf = (unsigned short*)(scale + B_ * M_); // 16*81920 u16

    gate_kernel<<<B_ * 32, 320, 0, stream>>>(positions, target, w1, b1, w2, b2,
                                             wf, scale);

    dim3 grid((T_ + TW - 1) / TW, B_);   // 16 x 16 = 256 blocks, 1/CU
    merge_gemm<<<grid, 512, 0, stream>>>(x, wf, scale, out);
}